// Round 10
// baseline (644.838 us; speedup 1.0000x reference)
//
#include <hip/hip_runtime.h>
#include <hip/hip_bf16.h>
#include <math.h>

// Problem constants (fixed by setup_inputs)
#define B_ 2
#define N_ 4096
#define D_ 2048
#define H_ 16
#define DH_ 128
#define CHUNK_ 256
#define NC_ 16
#define M_ (B_*N_)          // 8192 tokens
#define F3D (3*D_)          // 6144

typedef __bf16 v8bf __attribute__((ext_vector_type(8)));
typedef float  v4f  __attribute__((ext_vector_type(4)));
typedef unsigned short u16x8 __attribute__((ext_vector_type(8)));

__device__ __forceinline__ float bf2f(unsigned short u) {
    union { unsigned int i; float f; } c; c.i = ((unsigned int)u) << 16; return c.f;
}
__device__ __forceinline__ unsigned short f2bf(float f) {
    __hip_bfloat16 h = __float2bfloat16(f);
    return *(unsigned short*)&h;
}

// Measured-good form ONLY: offset imm = 0 (learn_hip m03/m97; r8 proved non-zero
// offset imm corrupts the transfer on gfx950).
__device__ __forceinline__ void async_copy16(void* lds, const void* g) {
    __builtin_amdgcn_global_load_lds(
        (const __attribute__((address_space(1))) unsigned int*)g,
        (__attribute__((address_space(3))) unsigned int*)lds,
        16, 0, 0);
}

// ---------------- RMSNorm: x (f32) -> xn (bf16), 8 elems/thread ----------------
__global__ __launch_bounds__(256) void k_rmsnorm(const float* __restrict__ x,
                                                 const float* __restrict__ scale,
                                                 __hip_bfloat16* __restrict__ xn)
{
    __shared__ float red[4];
    const int row = blockIdx.x;
    const float4* x4 = (const float4*)(x + (size_t)row * D_);
    float4 a = x4[threadIdx.x*2];
    float4 b = x4[threadIdx.x*2 + 1];
    float ss = a.x*a.x + a.y*a.y + a.z*a.z + a.w*a.w
             + b.x*b.x + b.y*b.y + b.z*b.z + b.w*b.w;
    #pragma unroll
    for (int off = 32; off > 0; off >>= 1) ss += __shfl_down(ss, off, 64);
    if ((threadIdx.x & 63) == 0) red[threadIdx.x >> 6] = ss;
    __syncthreads();
    float tot = red[0] + red[1] + red[2] + red[3];
    float r = rsqrtf(tot / (float)D_ + 1e-6f);
    const float4* s4 = (const float4*)scale;
    float4 sa = s4[threadIdx.x*2];
    float4 sb = s4[threadIdx.x*2 + 1];
    float v[8] = { sa.x*a.x, sa.y*a.y, sa.z*a.z, sa.w*a.w,
                   sb.x*b.x, sb.y*b.y, sb.z*b.z, sb.w*b.w };
    u16x8 o;
    #pragma unroll
    for (int j = 0; j < 8; ++j) {
        float t = fminf(fmaxf(v[j]*r, -60000.f), 60000.f);
        o[j] = f2bf(t);
    }
    ((u16x8*)(xn + (size_t)row * D_))[threadIdx.x] = o;
}

// ---------------- merged: depthwise conv+SiLU (blocks 0..8191) | weight casts ----------
#define W1_VECS 1572864   // 6144*2048/8
__global__ __launch_bounds__(256) void k_prep(const __hip_bfloat16* __restrict__ xn,
                                              const float* __restrict__ w,
                                              const float* __restrict__ bias,
                                              __hip_bfloat16* __restrict__ xc,
                                              const float* __restrict__ s1,
                                              __hip_bfloat16* __restrict__ d1,
                                              const float* __restrict__ s2,
                                              __hip_bfloat16* __restrict__ d2)
{
    if (blockIdx.x < 8192) {
        size_t p = (size_t)blockIdx.x * 256 + threadIdx.x;  // over M*D/8
        size_t e0 = p * 8;
        int d0 = (int)(e0 & (D_-1));
        int n  = (int)((e0 >> 11) & (N_-1));
        const float4* w4 = (const float4*)w;
        float acc[8];
        const float4* b4 = (const float4*)(bias + d0);
        float4 ba = b4[0], bb = b4[1];
        acc[0]=ba.x; acc[1]=ba.y; acc[2]=ba.z; acc[3]=ba.w;
        acc[4]=bb.x; acc[5]=bb.y; acc[6]=bb.z; acc[7]=bb.w;
        float4 wv[8];
        #pragma unroll
        for (int j = 0; j < 8; ++j) wv[j] = w4[d0 + j];
        #pragma unroll
        for (int k = 0; k < 4; ++k) {
            int nn = n - 3 + k;
            if (nn >= 0) {
                u16x8 t = *(const u16x8*)(xn + e0 - (size_t)(3-k)*D_);
                #pragma unroll
                for (int j = 0; j < 8; ++j) {
                    float wk = (k==0)?wv[j].x:(k==1)?wv[j].y:(k==2)?wv[j].z:wv[j].w;
                    acc[j] += bf2f(t[j]) * wk;
                }
            }
        }
        u16x8 o;
        #pragma unroll
        for (int j = 0; j < 8; ++j) {
            float s = acc[j] / (1.f + __expf(-acc[j]));
            o[j] = f2bf(s);
        }
        *(u16x8*)(xc + e0) = o;
    } else {
        size_t p = (size_t)(blockIdx.x - 8192) * 256 + threadIdx.x;
        const float* src; __hip_bfloat16* dst; size_t q;
        if (p < W1_VECS) { src = s1; dst = d1; q = p; }
        else             { src = s2; dst = d2; q = p - W1_VECS; }
        const float4* s4 = (const float4*)src;
        float4 a = s4[q*2], b = s4[q*2 + 1];
        u16x8 o;
        o[0]=f2bf(a.x); o[1]=f2bf(a.y); o[2]=f2bf(a.z); o[3]=f2bf(a.w);
        o[4]=f2bf(b.x); o[5]=f2bf(b.y); o[6]=f2bf(b.z); o[7]=f2bf(b.w);
        ((u16x8*)dst)[q] = o;
    }
}

// ---------------- bf16 NT GEMM: acc[m][n] = sum_k A[m][k] * W[n][k], K=2048 ----------
// r9-verified (795 TF): m97-style 2-buffer drain pipeline, addressing hoisted out of
// the K-loop. 128x128 tile, BK=32, 4 waves, 32 KiB LDS -> 4 blocks/CU.
// Conflict-free packed-pair swizzle (SQ_LDS_BANK_CONFLICT=0). No XCD swizzle.
// MODE 0: in_proj — stream 0: la = -clip(softplus(acc+dt_bias),0.001,2) (bf16)
//                   stream 1: v raw (bf16);  stream 2: sigmoid -> gate (bf16)
// MODE 1: out_proj — out[off] = acc + resid[off]  (f32)
template<int MODE>
__global__ __launch_bounds__(256, 4) void k_gemm(const __hip_bfloat16* __restrict__ Abf,
                                              const __hip_bfloat16* __restrict__ Wbf,
                                              __hip_bfloat16* __restrict__ o0,
                                              __hip_bfloat16* __restrict__ o1,
                                              __hip_bfloat16* __restrict__ o2,
                                              const float* __restrict__ dt_bias,
                                              const float* __restrict__ resid,
                                              float* __restrict__ outp)
{
    __shared__ __attribute__((aligned(16))) char lds[2][2][8192];
    const __bf16* A = (const __bf16*)Abf;
    const __bf16* W = (const __bf16*)Wbf;
    const int tid  = threadIdx.x;
    const int wave = tid >> 6;
    const int lane = tid & 63;
    const size_t m0 = (size_t)blockIdx.x * 128;
    const size_t n0 = (size_t)blockIdx.y * 128;
    const int wm = (wave & 1) * 64;
    const int wn = (wave >> 1) * 64;

    v4f acc[4][4] = {};

    const int fr = lane & 15;
    const int qk = lane >> 4;
    int mA = wm + fr, rA = mA >> 1;
    int mB = wn + fr, rB = mB >> 1;
    const char* vA = &lds[0][0][0] + rA*128 + (((((mA&1)<<2)|qk) ^ (rA&7)) << 4);
    const char* vB = &lds[0][1][0] + rB*128 + (((((mB&1)<<2)|qk) ^ (rB&7)) << 4);

    const int srL = lane >> 3, ssL = lane & 7;
    const __bf16 *sA0, *sA1, *sB0, *sB1;
    {
        int r0 = wave*8 + srL,      u0 = ssL ^ (r0 & 7);
        int r1 = 32 + wave*8 + srL, u1 = ssL ^ (r1 & 7);
        int ma0 = 2*r0 + (u0 >> 2), kg0 = u0 & 3;
        int ma1 = 2*r1 + (u1 >> 2), kg1 = u1 & 3;
        sA0 = A + (m0 + ma0)*(size_t)2048 + kg0*8;
        sA1 = A + (m0 + ma1)*(size_t)2048 + kg1*8;
        sB0 = W + (n0 + ma0)*(size_t)2048 + kg0*8;
        sB1 = W + (n0 + ma1)*(size_t)2048 + kg1*8;
    }
    char* dA0 = &lds[0][0][0] + wave*1024;
    char* dB0 = &lds[0][1][0] + wave*1024;

    #define STAGE(BUF) do { \
        async_copy16(dA0 + (BUF)*16384,        sA0); \
        async_copy16(dA0 + (BUF)*16384 + 4096, sA1); \
        async_copy16(dB0 + (BUF)*16384,        sB0); \
        async_copy16(dB0 + (BUF)*16384 + 4096, sB1); \
        sA0 += 32; sA1 += 32; sB0 += 32; sB1 += 32; } while(0)

    STAGE(0);

    for (int i2 = 0; i2 < 32; ++i2) {
        asm volatile("s_waitcnt vmcnt(0)" ::: "memory");
        __builtin_amdgcn_s_barrier();
        __builtin_amdgcn_sched_barrier(0);
        STAGE(1);
        {
            v8bf fa[4], fb[4];
            #pragma unroll
            for (int i = 0; i < 4; ++i) fa[i] = *(const v8bf*)(vA + i*1024);
            #pragma unroll
            for (int j = 0; j < 4; ++j) fb[j] = *(const v8bf*)(vB + j*1024);
            __builtin_amdgcn_s_setprio(1);
            #pragma unroll
            for (int i = 0; i < 4; ++i)
                #pragma unroll
                for (int j = 0; j < 4; ++j)
                    acc[i][j] = __builtin_amdgcn_mfma_f32_16x16x32_bf16(fa[i], fb[j], acc[i][j], 0, 0, 0);
            __builtin_amdgcn_s_setprio(0);
        }
        asm volatile("s_waitcnt vmcnt(0)" ::: "memory");
        __builtin_amdgcn_s_barrier();
        __builtin_amdgcn_sched_barrier(0);
        if (i2 + 1 < 32) STAGE(0);
        {
            v8bf fa[4], fb[4];
            #pragma unroll
            for (int i = 0; i < 4; ++i) fa[i] = *(const v8bf*)(vA + 16384 + i*1024);
            #pragma unroll
            for (int j = 0; j < 4; ++j) fb[j] = *(const v8bf*)(vB + 16384 + j*1024);
            __builtin_amdgcn_s_setprio(1);
            #pragma unroll
            for (int i = 0; i < 4; ++i)
                #pragma unroll
                for (int j = 0; j < 4; ++j)
                    acc[i][j] = __builtin_amdgcn_mfma_f32_16x16x32_bf16(fa[i], fb[j], acc[i][j], 0, 0, 0);
            __builtin_amdgcn_s_setprio(0);
        }
    }
    #undef STAGE

    // epilogue: C/D layout col=lane&15, row=(lane>>4)*4+r  (m89-verified)
    const int col = lane & 15;
    const int rb  = (lane >> 4) * 4;
    if (MODE == 0) {
        const int stream = blockIdx.y >> 4;
        const size_t nb = n0 - (size_t)stream * D_;
        #pragma unroll
        for (int i = 0; i < 4; ++i)
            #pragma unroll
            for (int j = 0; j < 4; ++j) {
                size_t nIdx = nb + wn + j*16 + col;
                #pragma unroll
                for (int r = 0; r < 4; ++r) {
                    size_t m = m0 + wm + i*16 + rb + r;
                    size_t off = m * (size_t)D_ + nIdx;
                    float v = acc[i][j][r];
                    if (stream == 0) {
                        float xx = v + dt_bias[nIdx];
                        float e  = __expf(-fabsf(xx));
                        float sp = fmaxf(xx, 0.f) + __logf(1.f + e);
                        float dt = fminf(fmaxf(sp, 0.001f), 2.0f);
                        o0[off] = __float2bfloat16(-dt);                  // la (bf16)
                    } else if (stream == 1) {
                        o1[off] = __float2bfloat16(v);                    // raw v
                    } else {
                        o2[off] = __float2bfloat16(1.f/(1.f+__expf(-v))); // gate
                    }
                }
            }
    } else {
        #pragma unroll
        for (int i = 0; i < 4; ++i)
            #pragma unroll
            for (int j = 0; j < 4; ++j)
                #pragma unroll
                for (int r = 0; r < 4; ++r) {
                    size_t m = m0 + wm + i*16 + rb + r;
                    size_t off = m * (size_t)D_ + n0 + wn + j*16 + col;
                    outp[off] = acc[i][j][r] + resid[off];
                }
    }
}

// ---------------- scan, half-split: 2 threads per (b,c,d), 128 steps each ----------
// L_t = max(S_t,-20) with S a PLAIN cumsum (la<0 -> upper clip never binds) => S is
// associative: half-B only needs half-A's SUM for absolute L. Phase 1: each thread
// sums its own half's la (warms L2); LDS pair-exchange gives B its S offset.
// Phase 2: both halves scan 128 steps. Writes nc (bf16, local out), expL (bf16),
// and per-HALF boundary (bdH,boH). Cross-half out-mass is restored exactly in
// scan2/hmix: nc256_t(B) = outB_t + boA*e^{L_t-bdA} => carrB = carr_c + boA*e^{-bdA}.
__global__ __launch_bounds__(256) void k_scan1(const __hip_bfloat16* __restrict__ la,
                                               const __hip_bfloat16* __restrict__ v,
                                               float* __restrict__ bdH, float* __restrict__ boH,
                                               __hip_bfloat16* __restrict__ nc,
                                               __hip_bfloat16* __restrict__ expL)
{
    __shared__ float hsum[256];
    const int lanePair = threadIdx.x & 127;
    const int half = threadIdx.x >> 7;
    int pairIdx = blockIdx.x * 128 + lanePair;   // over B*NC*D = 65536
    int d = pairIdx & (D_-1);
    int c = (pairIdx >> 11) & (NC_-1);
    int b = pairIdx >> 15;
    size_t rowH = (size_t)b * N_ + (size_t)c * CHUNK_ + half*128;

    // phase 1: own-half sum
    float S0 = 0.f;
    #pragma unroll 8
    for (int t = 0; t < 128; ++t)
        S0 += __bfloat162float(la[(rowH + t) * (size_t)D_ + d]);
    hsum[threadIdx.x] = S0;
    __syncthreads();
    float S = half ? hsum[lanePair] : 0.f;       // B starts at A's sum

    int i = d & 63;
    const bool fh = (d & 64) == 0;
    float inv = __expf((float)i * (-9.210340371976184f / 64.f)); // 10000^(-i/64)
    int n0 = c * CHUNK_ + half * 128;
    float cs = cosf((float)n0 * inv), sn = sinf((float)n0 * inv);
    float ca = cosf(inv), sa = sinf(inv);
    float Lp = 0.f, out = 0.f;
    #pragma unroll 8
    for (int t = 0; t < 128; ++t) {
        size_t off = (rowH + t) * (size_t)D_ + d;
        float a  = __bfloat162float(la[off]);
        float vo = __bfloat162float(v[off]);
        float vp = __bfloat162float(v[fh ? off + 64 : off - 64]);
        float dt = -a;
        float vin = (fh ? (vo*cs - vp*sn) : (vp*sn + vo*cs)) * dt;
        S += a;
        float L = fmaxf(S, -20.f);
        out = __expf(L - Lp) * out + vin;        // first iter: out==0, exp<=1 safe
        Lp = L;
        nc[off]   = __float2bfloat16(out);
        expL[off] = __float2bfloat16(__expf(L));
        float csn = cs*ca - sn*sa;
        sn = sn*ca + cs*sa;
        cs = csn;
    }
    size_t hIdx = ((size_t)(b*NC_ + c)*2 + half)*D_ + d;
    bdH[hIdx] = Lp;
    boH[hIdx] = out;
}

// ---------------- scan phase 2: combine halves -> chunks -> per-half carries ------
__global__ __launch_bounds__(256) void k_scan2(const float* __restrict__ bdH,
                                               const float* __restrict__ boH,
                                               float* __restrict__ carrH)
{
    int idx = blockIdx.x * 256 + threadIdx.x;   // B*D = 4096
    int d = idx & (D_-1);
    int b = idx >> 11;
    auto HIX = [&](int c, int h) { return ((size_t)(b*NC_ + c)*2 + h)*D_ + d; };
    float bd0 = bdH[HIX(0,1)];                  // chunk-0 full bd (half B end)
    float cd = 0.f, acc = 0.f;
    #pragma unroll
    for (int c = 0; c < NC_; ++c) {
        float bdA = bdH[HIX(c,0)], boA = boH[HIX(c,0)];
        float bdB = bdH[HIX(c,1)], boB = boH[HIX(c,1)];
        float bo_c = boB + boA * __expf(bdB - bdA);  // chunk-end out (exact telescope)
        cd = fmaxf(cd + bdB, -80.f);                 // clip(cumsum(bd),-80,0)
        float ncd = fmaxf(cd - bd0, -20.f);          // clip(cd-stab,-20,0)
        float carr = acc * __expf(ncd);              // seeds strictly before c
        carrH[HIX(c,0)] = carr;                      // half A: unchanged form
        carrH[HIX(c,1)] = carr + boA * __expf(-bdA); // half B: + cross-half mass
        acc += bo_c * __expf(-ncd);
    }
}

// ---------------- fused: state = nc + carrH*expL, head_mix, * gate -> y (bf16) -------
__global__ __launch_bounds__(256) void k_hmix(const __hip_bfloat16* __restrict__ nc,
                                              const __hip_bfloat16* __restrict__ expL,
                                              const float* __restrict__ carrH,
                                              const __hip_bfloat16* __restrict__ gate,
                                              const float* __restrict__ hm,
                                              __hip_bfloat16* __restrict__ y)
{
    __shared__ float lf[D_];
    __shared__ float lhm[H_*H_];
    const int row = blockIdx.x;
    const size_t base = (size_t)row * D_;
    const int b  = row >> 12;                // N_=4096 rows per batch
    const int c  = (row >> 8) & (NC_-1);     // chunk
    const int hf = (row >> 7) & 1;           // half within chunk
    const float* cp = carrH + ((size_t)(b*NC_ + c)*2 + hf) * D_ + threadIdx.x*8;
    u16x8 el = ((const u16x8*)(expL + base))[threadIdx.x];
    u16x8 n8 = ((const u16x8*)(nc + base))[threadIdx.x];
    const float4* c4 = (const float4*)cp;
    float4 ca = c4[0], cb = c4[1];
    float cv[8] = { ca.x, ca.y, ca.z, ca.w, cb.x, cb.y, cb.z, cb.w };
    #pragma unroll
    for (int j = 0; j < 8; ++j)
        lf[threadIdx.x*8 + j] = bf2f(n8[j]) + cv[j] * bf2f(el[j]);
    lhm[threadIdx.x] = hm[threadIdx.x];      // H*H = 256 = blockDim
    __syncthreads();
    #pragma unroll
    for (int k = 0; k < 8; ++k) {
        int o = threadIdx.x + k*256;
        int m  = o >> 7;
        int dh = o & 127;
        float s = 0.f;
        #pragma unroll
        for (int h = 0; h < H_; ++h) s += lf[h*DH_ + dh] * lhm[h*H_ + m];
        float g = __bfloat162float(gate[base + o]);
        y[base + o] = __float2bfloat16(s * g);
    }
}

extern "C" void kernel_launch(void* const* d_in, const int* in_sizes, int n_in,
                              void* d_out, int out_size, void* d_ws, size_t ws_size,
                              hipStream_t stream)
{
    const float* x          = (const float*)d_in[0];
    const float* norm_scale = (const float*)d_in[1];
    const float* conv_w     = (const float*)d_in[2];
    const float* conv_b     = (const float*)d_in[3];
    const float* in_proj_w  = (const float*)d_in[4];
    const float* dt_bias    = (const float*)d_in[5];
    const float* head_mix   = (const float*)d_in[6];
    const float* out_proj_w = (const float*)d_in[7];
    float* out = (float*)d_out;

    // Workspace layout — total 176,947,200 B.
    char* ws = (char*)d_ws;
    __hip_bfloat16* la   = (__hip_bfloat16*)ws;                      // 33.5MB; -> y after scan1
    float*          bdH  = (float*)(ws + 33554432);                  // 512KB (B*NC*2*D f32)
    float*          boH  = (float*)(ws + 34078720);                  // 512KB
    float*          carrH= (float*)(ws + 34603008);                  // 512KB
    __hip_bfloat16* xn   = (__hip_bfloat16*)(ws + 67108864);         // 33.5MB; -> w1 -> nc
    __hip_bfloat16* xc   = (__hip_bfloat16*)(ws + 100663296);        // 33.5MB (dead after GEMM1)
    __hip_bfloat16* gate = (__hip_bfloat16*)(ws + 134217728);        // 33.5MB
    __hip_bfloat16* w2   = (__hip_bfloat16*)(ws + 167772160);        //  8.4MB
    __hip_bfloat16* w1   = xn;   // xn dead after conv
    // nc (bf16 now, 33.5MB) reuses the w1/xn region — w1 dead after GEMM1.
    __hip_bfloat16* nc   = (__hip_bfloat16*)(ws + 67108864);
    // y reuses the la region (la dead after scan1).
    __hip_bfloat16* y    = (__hip_bfloat16*)ws;
    // d_out scratch: v (first half); stex = expL (second half); dead before GEMM2.
    __hip_bfloat16* v     = (__hip_bfloat16*)d_out;
    __hip_bfloat16* stex  = (__hip_bfloat16*)((char*)d_out + 33554432);

    k_rmsnorm<<<M_, 256, 0, stream>>>(x, norm_scale, xn);
    k_prep<<<16384, 256, 0, stream>>>(xn, conv_w, conv_b, xc,
                                      in_proj_w, w1, out_proj_w, w2);
    k_gemm<0><<<dim3(M_/128, F3D/128), 256, 0, stream>>>(xc, w1, la, v, gate, dt_bias, nullptr, nullptr);
    k_scan1<<<(B_*NC_*D_*2)/256, 256, 0, stream>>>(la, v, bdH, boH, nc, stex);
    k_scan2<<<(B_*D_)/256, 256, 0, stream>>>(bdH, boH, carrH);
    k_hmix<<<M_, 256, 0, stream>>>(nc, stex, carrH, gate, head_mix, y);
    k_gemm<1><<<dim3(M_/128, D_/128), 256, 0, stream>>>(y, w2, nullptr, nullptr, nullptr, nullptr, x, out);
}